// Round 4
// baseline (462.560 us; speedup 1.0000x reference)
//
#include <hip/hip_runtime.h>
#include <math.h>

#define LNUM 6
#define BNUM 8
#define NNUM 300
#define CNUM 20
#define HW   784
#define HW4  196   // HW/4
#define GH   448
#define NW   16    // mask words per (b,n): permuted bit order (popcount-invariant)
#define AW   5     // adjacency row words (300 bits -> 5 x u64)
#define RT   8     // bce rows per unit
#define TPB  56    // tiles per (b,c): 448/8
#define GRID 1024  // exactly 4 blocks/CU * 256 CU -> co-resident (launch_bounds enforces)
#define RM_UNITS  (BNUM*NNUM)        // 2400
#define CM_UNITS  (BNUM*CNUM)        // 160
#define BCE_UNITS (BNUM*CNUM*TPB)    // 8960

// ---- device scratch (every consumed entry rewritten each launch) ----
__device__ float              g_rm [BNUM*NNUM*HW];
__device__ unsigned long long g_T  [BNUM*NNUM*NW];
__device__ int                g_s  [BNUM*NNUM];
__device__ unsigned long long g_adj[BNUM*NNUM*AW];
__device__ float              g_mm [BNUM*CNUM*HW];
__device__ double             g_part[GRID];
__device__ int                g_bar_cnt   = 0;   // always returns to 0
__device__ int                g_bar_sense = 0;   // read dynamically at kernel start -> replay-safe

struct SmRm  { float wmax[4]; int scount; };
struct SmAdj { unsigned long long Ti[NW]; int si; };
struct SmCm  { unsigned long long adj[NNUM][AW];
               unsigned long long cand[AW], fin[AW], nwv[AW];
               int has, go; float cf; };
struct SmBce { float m[HW]; float rowY[RT*28]; double wsum[4]; };
union  SmU   { SmRm rm; SmAdj adj; SmCm cm; SmBce bce; double fw[4]; };

// Sense-reversing grid barrier, device scope (handles cross-XCD L2 via sc1/wbl2/inv
// emitted by agent-scope atomics per the gfx940+ memory model).
__device__ __forceinline__ void grid_bar(int& sense) {
    int s = sense ^ 1;
    sense = s;
    __syncthreads();                 // all block stores complete to L2
    if (threadIdx.x == 0) {
        int prev = __hip_atomic_fetch_add(&g_bar_cnt, 1, __ATOMIC_ACQ_REL, __HIP_MEMORY_SCOPE_AGENT);
        if (prev == GRID - 1) {
            __hip_atomic_store(&g_bar_cnt, 0, __ATOMIC_RELAXED, __HIP_MEMORY_SCOPE_AGENT);
            __hip_atomic_store(&g_bar_sense, s, __ATOMIC_RELEASE, __HIP_MEMORY_SCOPE_AGENT);
        } else {
            while (__hip_atomic_load(&g_bar_sense, __ATOMIC_RELAXED, __HIP_MEMORY_SCOPE_AGENT) != s)
                __builtin_amdgcn_s_sleep(2);
        }
    }
    __syncthreads();
    __builtin_amdgcn_fence(__ATOMIC_ACQUIRE, "agent");   // invalidate L1 for all waves
}

__global__ void __launch_bounds__(256, 4)
k_fused(const float* __restrict__ smap, const float* __restrict__ score,
        const int* __restrict__ label, const int* __restrict__ gt,
        float* __restrict__ out) {
    __shared__ SmU sm;
    const int tid  = threadIdx.x;
    const int lane = tid & 63, wid = tid >> 6;
    const int bid  = blockIdx.x;
    int sense = __hip_atomic_load(&g_bar_sense, __ATOMIC_RELAXED, __HIP_MEMORY_SCOPE_AGENT);

    // ================= phase 1: rm (mean/L, relu, max-norm, mask bits) =================
    for (int u = bid; u < RM_UNITS; u += GRID) {
        if (tid == 0) sm.rm.scount = 0;
        const size_t lstr4 = (size_t)BNUM * NNUM * HW4;
        const float4* base = (const float4*)smap + (size_t)u * HW4;
        bool act = tid < HW4;
        float4 v = {0.f, 0.f, 0.f, 0.f};
        if (act) {
            float4 a = {0.f, 0.f, 0.f, 0.f};
            #pragma unroll
            for (int l = 0; l < LNUM; ++l) {
                float4 x = base[(size_t)l * lstr4 + tid];
                a.x += x.x; a.y += x.y; a.z += x.z; a.w += x.w;
            }
            v.x = fmaxf(__fdiv_rn(a.x, 6.0f), 0.0f);
            v.y = fmaxf(__fdiv_rn(a.y, 6.0f), 0.0f);
            v.z = fmaxf(__fdiv_rn(a.z, 6.0f), 0.0f);
            v.w = fmaxf(__fdiv_rn(a.w, 6.0f), 0.0f);
        }
        float lm = fmaxf(fmaxf(v.x, v.y), fmaxf(v.z, v.w));
        #pragma unroll
        for (int off = 32; off; off >>= 1) lm = fmaxf(lm, __shfl_xor(lm, off));
        if (lane == 0) sm.rm.wmax[wid] = lm;
        __syncthreads();                  // wmax ready, scount reset visible
        float mx = fmaxf(fmaxf(sm.rm.wmax[0], sm.rm.wmax[1]), fmaxf(sm.rm.wmax[2], sm.rm.wmax[3]));
        float d = mx + 1e-6f;
        float4 nv;
        nv.x = __fdiv_rn(v.x, d); nv.y = __fdiv_rn(v.y, d);
        nv.z = __fdiv_rn(v.z, d); nv.w = __fdiv_rn(v.w, d);
        if (act) ((float4*)g_rm)[(size_t)u * HW4 + tid] = nv;
        float cc[4] = {nv.x, nv.y, nv.z, nv.w};
        #pragma unroll
        for (int k = 0; k < 4; ++k) {
            bool pr = act && (cc[k] > 0.7f);
            unsigned long long ball = __ballot(pr);
            if (lane == 0) {
                g_T[(size_t)u * NW + k * 4 + wid] = ball;
                atomicAdd(&sm.rm.scount, __popcll(ball));
            }
        }
        __syncthreads();                  // scount complete
        if (tid == 0) g_s[u] = sm.rm.scount;
    }
    grid_bar(sense);

    // ================= phase 2: adjacency =================
    for (int u = bid; u < RM_UNITS; u += GRID) {
        __syncthreads();                  // previous unit's Ti readers done
        if (tid < NW)  sm.adj.Ti[tid] = g_T[(size_t)u * NW + tid];
        if (tid == NW) sm.adj.si = g_s[u];
        __syncthreads();
        int b = u / NNUM;
        for (int word = wid; word < AW; word += 4) {  // wave0: words 0,4; waves1-3: 1,2,3
            int j = word * 64 + lane;
            bool a = false;
            if (j < NNUM) {
                const unsigned long long* Tj = &g_T[((size_t)b * NNUM + j) * NW];
                int inter = 0;
                #pragma unroll
                for (int w = 0; w < NW; ++w) inter += __popcll(sm.adj.Ti[w] & Tj[w]);
                int si = sm.adj.si, sj = g_s[b * NNUM + j];
                int uni = si + sj - inter, tot = si + sj;
                float iou  = (uni == 0) ? 1.0f : __fdiv_rn((float)inter, (float)uni);
                float dice = (tot == 0) ? 1.0f : __fdiv_rn(2.0f * (float)inter, (float)tot);
                a = (0.5f * (iou + dice)) > 0.5f;
            }
            unsigned long long ball = __ballot(a);
            if (lane == 0) g_adj[(size_t)u * AW + word] = ball;
        }
    }
    grid_bar(sense);

    // ================= phase 3: cluster + meanmap (160 blocks) =================
    if (bid < CM_UNITS && label[bid] != 0) {
        int blk = bid;
        int b = blk / CNUM, c = blk - b * CNUM;
        for (int idx = tid; idx < NNUM * AW; idx += 256)
            ((unsigned long long*)sm.cm.adj)[idx] = g_adj[(size_t)b * NNUM * AW + idx];
        if (wid == 0) {
            float bv = -INFINITY; int bi = NNUM;     // masked argmax
            float bva = -INFINITY; int bia = NNUM;   // unmasked fallback argmax
            for (int k = 0; k < AW; ++k) {
                int j = k * 64 + lane;
                bool cb = false;
                if (j < NNUM) {
                    float sc = score[((size_t)b * NNUM + j) * CNUM + c];
                    if (sc > bva) { bva = sc; bia = j; }   // strict > keeps first occurrence
                    cb = sc > 0.01f;
                    if (cb && sc > bv) { bv = sc; bi = j; }
                }
                unsigned long long ball = __ballot(cb);
                if (lane == 0) sm.cm.cand[k] = ball;
            }
            #pragma unroll
            for (int off = 1; off < 64; off <<= 1) {
                float ov = __shfl_xor(bv, off);  int oi = __shfl_xor(bi, off);
                if (ov > bv || (ov == bv && oi < bi)) { bv = ov; bi = oi; }
                float ova = __shfl_xor(bva, off); int oia = __shfl_xor(bia, off);
                if (ova > bva || (ova == bva && oia < bia)) { bva = ova; bia = oia; }
            }
            bool has = (sm.cm.cand[0] | sm.cm.cand[1] | sm.cm.cand[2] |
                        sm.cm.cand[3] | sm.cm.cand[4]) != 0ULL;
            if (lane == 0) sm.cm.has = has ? 1 : 0;
            if (has) {
                if (lane < AW) sm.cm.fin[lane] = sm.cm.cand[lane] & sm.cm.adj[bi][lane];
            } else {
                if (lane < AW) sm.cm.fin[lane] = ((bia >> 6) == lane) ? (1ULL << (bia & 63)) : 0ULL;
            }
        }
        __syncthreads();
        if (sm.cm.has) {
            for (int it = 0; it < NNUM + 2; ++it) {
                if (wid == 0) {
                    for (int k = 0; k < AW; ++k) {
                        int j = k * 64 + lane;
                        bool nb = false;
                        if (j < NNUM && ((sm.cm.cand[k] >> lane) & 1ULL)) {
                            unsigned long long o =
                                (sm.cm.adj[j][0] & sm.cm.fin[0]) | (sm.cm.adj[j][1] & sm.cm.fin[1]) |
                                (sm.cm.adj[j][2] & sm.cm.fin[2]) | (sm.cm.adj[j][3] & sm.cm.fin[3]) |
                                (sm.cm.adj[j][4] & sm.cm.fin[4]);
                            nb = (o != 0ULL);   // adj symmetric
                        }
                        unsigned long long ball = __ballot(nb);
                        if (lane == 0) sm.cm.nwv[k] = ball;
                    }
                    bool ch = (lane < AW) && (sm.cm.nwv[lane] != sm.cm.fin[lane]);
                    unsigned long long chb = __ballot(ch);
                    if (lane == 0) sm.cm.go = (chb != 0ULL) ? 1 : 0;
                    if (lane < AW) sm.cm.fin[lane] = sm.cm.nwv[lane];
                }
                __syncthreads();
                int go = sm.cm.go;
                __syncthreads();          // all read go before wave0 rewrites it
                if (!go) break;
            }
        }
        if (tid == 0) {
            int cs = 0;
            for (int w = 0; w < AW; ++w) cs += __popcll(sm.cm.fin[w]);
            sm.cm.cf = (float)cs;
        }
        __syncthreads();
        if (tid < HW4) {
            float4 a = {0.f, 0.f, 0.f, 0.f};
            for (int w = 0; w < AW; ++w) {
                unsigned long long word = sm.cm.fin[w];
                while (word) {
                    int j = w * 64 + (__ffsll(word) - 1);
                    word &= word - 1;
                    float4 r = ((const float4*)g_rm)[((size_t)b * NNUM + j) * HW4 + tid];
                    a.x += r.x; a.y += r.y; a.z += r.z; a.w += r.w;
                }
            }
            float cdiv = sm.cm.cf;
            float4 o;
            o.x = __fdiv_rn(a.x, cdiv); o.y = __fdiv_rn(a.y, cdiv);
            o.z = __fdiv_rn(a.z, cdiv); o.w = __fdiv_rn(a.w, cdiv);
            ((float4*)g_mm)[(size_t)blk * HW4 + tid] = o;
        }
    }
    grid_bar(sense);

    // ================= phase 4: bilinear upsample + BCE =================
    double bacc = 0.0;
    for (int u = bid; u < BCE_UNITS; u += GRID) {
        int bc = u / TPB, tile = u - bc * TPB;
        if (label[bc] == 0) continue;     // block-uniform
        int b = bc / CNUM, c = bc - b * CNUM;
        if (tid < HW4) ((float4*)sm.bce.m)[tid] = ((const float4*)g_mm)[(size_t)bc * HW4 + tid];
        __syncthreads();
        int row0 = tile * RT;
        if (tid < RT * 28) {
            int r = tid / 28, x = tid - r * 28;
            int oy = row0 + r;
            float iy = fmaf((float)oy, 0.0625f, -0.46875f);   // (oy+0.5)/16-0.5, exact
            float y0f = floorf(iy);
            float wy = iy - y0f;
            int y0 = (int)y0f;
            if (y0 < 0) { y0 = 0; wy = 0.0f; } else if (y0 > 26) { y0 = 26; wy = 1.0f; }
            float lo = sm.bce.m[y0 * 28 + x], hi = sm.bce.m[y0 * 28 + 28 + x];
            sm.bce.rowY[tid] = lo + wy * (hi - lo);
        }
        __syncthreads();
        double acc = 0.0;
        if (tid < RT * 28) {
            int r = tid / 28, j = tid - r * 28;
            const int* gr = gt + ((size_t)b * GH + row0 + r) * GH;
            int cp1 = c + 1;
            if (j < 27) {
                float rY0 = sm.bce.rowY[r * 28 + j], rY1 = sm.bce.rowY[r * 28 + j + 1];
                float sl = rY1 - rY0;
                const int4* gp = (const int4*)(gr + 16 * j + 8);
                #pragma unroll
                for (int q = 0; q < 4; ++q) {
                    int4 g4 = gp[q];
                    #pragma unroll
                    for (int uu = 0; uu < 4; ++uu) {
                        int k = q * 4 + uu;
                        int gv = (uu == 0) ? g4.x : (uu == 1) ? g4.y : (uu == 2) ? g4.z : g4.w;
                        float wk = fmaf((float)k, 0.0625f, 0.03125f);   // (2k+1)/32, exact
                        float pred = rY0 + wk * sl;
                        float xv = (gv == cp1) ? pred : 1.0f - pred;
                        float lg = __logf(fmaxf(xv, 1.175494351e-38f));
                        acc += (double)((xv > 0.0f) ? lg : -100.0f);
                    }
                }
            } else {
                #pragma unroll
                for (int side = 0; side < 2; ++side) {
                    float pred = sm.bce.rowY[r * 28 + (side ? 27 : 0)];
                    const int4* gp = (const int4*)(gr + (side ? 440 : 0));
                    int4 a0 = gp[0], a1 = gp[1];
                    int np = (a0.x == cp1) + (a0.y == cp1) + (a0.z == cp1) + (a0.w == cp1)
                           + (a1.x == cp1) + (a1.y == cp1) + (a1.z == cp1) + (a1.w == cp1);
                    float om = 1.0f - pred;
                    float lgp = (pred > 0.0f) ? __logf(fmaxf(pred, 1.175494351e-38f)) : -100.0f;
                    float lgn = (om   > 0.0f) ? __logf(fmaxf(om,   1.175494351e-38f)) : -100.0f;
                    acc += (double)lgp * (double)np + (double)lgn * (double)(8 - np);
                }
            }
        }
        #pragma unroll
        for (int off = 32; off; off >>= 1) acc += __shfl_xor(acc, off);
        if (lane == 0) sm.bce.wsum[wid] = acc;
        __syncthreads();
        if (tid == 0)
            bacc += sm.bce.wsum[0] + sm.bce.wsum[1] + sm.bce.wsum[2] + sm.bce.wsum[3];
        __syncthreads();
    }
    if (tid == 0) g_part[bid] = -bacc * (1.0 / (448.0 * 448.0));
    grid_bar(sense);

    // ================= phase 5: final reduce (block 0) =================
    if (bid == 0) {
        double s = 0.0;
        for (int i = tid; i < GRID; i += 256) s += g_part[i];
        #pragma unroll
        for (int off = 32; off; off >>= 1) s += __shfl_xor(s, off);
        if (lane == 0) sm.fw[wid] = s;
        __syncthreads();
        if (tid == 0) {
            int sa = 0;
            for (int i = 0; i < BNUM * CNUM; ++i) sa += (label[i] != 0) ? 1 : 0;
            out[0] = (float)((sm.fw[0] + sm.fw[1] + sm.fw[2] + sm.fw[3]) / (double)sa);
        }
    }
}

extern "C" void kernel_launch(void* const* d_in, const int* in_sizes, int n_in,
                              void* d_out, int out_size, void* d_ws, size_t ws_size,
                              hipStream_t stream) {
    const float* smap  = (const float*)d_in[0];   // (L,B,N,784)
    const float* score = (const float*)d_in[1];   // (B,N,C)
    const int*   label = (const int*)d_in[2];     // (B,C)
    const int*   gt    = (const int*)d_in[3];     // (B,448,448)
    float* out = (float*)d_out;

    hipLaunchKernelGGL(k_fused, dim3(GRID), dim3(256), 0, stream,
                       smap, score, label, gt, out);
}

// Round 5
// 189.796 us; speedup vs baseline: 2.4371x; 2.4371x over previous
//
#include <hip/hip_runtime.h>
#include <math.h>

#define LNUM 6
#define BNUM 8
#define NNUM 300
#define CNUM 20
#define HW   784
#define HW4  196   // HW/4
#define GH   448
#define NW   16    // mask words per (b,n): permuted bit order (popcount-invariant)
#define AW   5     // adjacency row words (300 bits -> 5 x u64)
#define RT   16    // bce rows per tile
#define NTILE 28   // 448/16 tiles per (b,c)
#define TOTBC  (BNUM*CNUM)          // 160
#define TOTBLK (TOTBC*NTILE)        // 4480

// ---- device scratch (every consumed entry rewritten each launch; counters self-reset) ----
__device__ float              g_rm [BNUM*NNUM*HW];
__device__ unsigned long long g_T  [BNUM*NNUM*NW];
__device__ int                g_s  [BNUM*NNUM];
__device__ unsigned long long g_adj[BNUM*NNUM*AW];
__device__ double             g_part[TOTBLK];     // inactive entries: never written, stay 0
__device__ int                g_tdone[TOTBC];     // tile-done per bc; reset by bc-finalizer
__device__ int                g_bdone = 0;        // bc-done; reset by overall-last

// One block per (b,n): mean over L (float4), relu, max-normalize, rm + bitmask + popcount.
__global__ void k_rm(const float* __restrict__ sm) {
    int bn  = blockIdx.x;
    int tid = threadIdx.x;               // 256
    int lane = tid & 63, wid = tid >> 6;
    __shared__ float wmax[4];
    __shared__ int   scount;
    if (tid == 0) scount = 0;
    const size_t lstr4 = (size_t)BNUM * NNUM * HW4;
    const float4* base = (const float4*)sm + (size_t)bn * HW4;
    bool act = tid < HW4;
    float4 v = {0.f, 0.f, 0.f, 0.f};
    if (act) {
        float4 a = {0.f, 0.f, 0.f, 0.f};
        #pragma unroll
        for (int l = 0; l < LNUM; ++l) {
            float4 x = base[(size_t)l * lstr4 + tid];
            a.x += x.x; a.y += x.y; a.z += x.z; a.w += x.w;
        }
        v.x = fmaxf(__fdiv_rn(a.x, 6.0f), 0.0f);
        v.y = fmaxf(__fdiv_rn(a.y, 6.0f), 0.0f);
        v.z = fmaxf(__fdiv_rn(a.z, 6.0f), 0.0f);
        v.w = fmaxf(__fdiv_rn(a.w, 6.0f), 0.0f);
    }
    float lm = fmaxf(fmaxf(v.x, v.y), fmaxf(v.z, v.w));
    #pragma unroll
    for (int off = 32; off; off >>= 1) lm = fmaxf(lm, __shfl_xor(lm, off));
    if (lane == 0) wmax[wid] = lm;
    __syncthreads();
    float mx = fmaxf(fmaxf(wmax[0], wmax[1]), fmaxf(wmax[2], wmax[3]));
    float d = mx + 1e-6f;
    float4 nv;
    nv.x = __fdiv_rn(v.x, d); nv.y = __fdiv_rn(v.y, d);
    nv.z = __fdiv_rn(v.z, d); nv.w = __fdiv_rn(v.w, d);
    if (act) ((float4*)g_rm)[(size_t)bn * HW4 + tid] = nv;
    float c[4] = {nv.x, nv.y, nv.z, nv.w};
    #pragma unroll
    for (int k = 0; k < 4; ++k) {
        bool pr = act && (c[k] > 0.7f);
        unsigned long long ball = __ballot(pr);
        if (lane == 0) {
            g_T[(size_t)bn * NW + k * 4 + wid] = ball;
            atomicAdd(&scount, __popcll(ball));
        }
    }
    __syncthreads();
    if (tid == 0) g_s[bn] = scount;
}

// One block per (b,i): adjacency row i via popcount(AND) + exact f32 (iou+dice)/2 > 0.5
__global__ void k_adj() {
    int blk = blockIdx.x;                // b*300 + i
    int b = blk / NNUM;
    int tid = threadIdx.x;               // 320 (5 waves)
    __shared__ unsigned long long Ti[NW];
    __shared__ int si_sh;
    if (tid < NW)  Ti[tid] = g_T[(size_t)blk * NW + tid];
    if (tid == NW) si_sh = g_s[blk];
    __syncthreads();
    bool a = false;
    int j = tid;
    if (j < NNUM) {
        const unsigned long long* Tj = &g_T[((size_t)b * NNUM + j) * NW];
        int inter = 0;
        #pragma unroll
        for (int w = 0; w < NW; ++w) inter += __popcll(Ti[w] & Tj[w]);
        int si = si_sh, sj = g_s[b * NNUM + j];
        int uni = si + sj - inter, tot = si + sj;
        float iou  = (uni == 0) ? 1.0f : __fdiv_rn((float)inter, (float)uni);
        float dice = (tot == 0) ? 1.0f : __fdiv_rn(2.0f * (float)inter, (float)tot);
        a = (0.5f * (iou + dice)) > 0.5f;
    }
    unsigned long long ball = __ballot(a);
    if ((tid & 63) == 0) g_adj[(size_t)blk * AW + (tid >> 6)] = ball;
}

// One block per (bc, tile): re-run cluster (wave 0), mini-meanmap (<=3 input rows),
// rowY, bce over 16 output rows. Spin-free hierarchical completion -> last block
// reduces g_part and writes out.
__global__ void __launch_bounds__(448)
k_bcf(const float* __restrict__ score, const int* __restrict__ label,
      const int* __restrict__ gt, float* __restrict__ out) {
    int blk = blockIdx.x;                // bc*NTILE + tile
    int bc = blk / NTILE, tile = blk - bc * NTILE;
    int b = bc / CNUM, c = bc - b * CNUM;
    int tid = threadIdx.x;               // 448 (7 waves)
    int lane = tid & 63, wid = tid >> 6;
    bool active = (label[bc] != 0);      // block-uniform

    __shared__ unsigned long long adj_sh[NNUM][AW];
    __shared__ unsigned long long cand[AW], fin[AW], nwv[AW];
    __shared__ int sh_has, sh_go, sh_last, sh_sa;
    __shared__ float sh_cf;
    __shared__ float mrow[3 * 28];
    __shared__ float rowY[RT * 28];
    __shared__ double wsum[7];

    if (active) {
        for (int idx = tid; idx < NNUM * AW; idx += 448)
            ((unsigned long long*)adj_sh)[idx] = g_adj[(size_t)b * NNUM * AW + idx];
        if (wid == 0) {
            float bv = -INFINITY; int bi = NNUM;     // masked argmax
            float bva = -INFINITY; int bia = NNUM;   // unmasked fallback argmax
            for (int k = 0; k < AW; ++k) {
                int j = k * 64 + lane;
                bool cb = false;
                if (j < NNUM) {
                    float sc = score[((size_t)b * NNUM + j) * CNUM + c];
                    if (sc > bva) { bva = sc; bia = j; }   // strict > keeps first occurrence
                    cb = sc > 0.01f;
                    if (cb && sc > bv) { bv = sc; bi = j; }
                }
                unsigned long long ball = __ballot(cb);
                if (lane == 0) cand[k] = ball;
            }
            #pragma unroll
            for (int off = 1; off < 64; off <<= 1) {
                float ov = __shfl_xor(bv, off);  int oi = __shfl_xor(bi, off);
                if (ov > bv || (ov == bv && oi < bi)) { bv = ov; bi = oi; }
                float ova = __shfl_xor(bva, off); int oia = __shfl_xor(bia, off);
                if (ova > bva || (ova == bva && oia < bia)) { bva = ova; bia = oia; }
            }
            bool has = (cand[0] | cand[1] | cand[2] | cand[3] | cand[4]) != 0ULL;
            if (lane == 0) sh_has = has ? 1 : 0;
            if (has) {
                if (lane < AW) fin[lane] = cand[lane] & adj_sh[bi][lane];
            } else {
                if (lane < AW) fin[lane] = ((bia >> 6) == lane) ? (1ULL << (bia & 63)) : 0ULL;
            }
        }
        __syncthreads();
        if (sh_has) {
            for (int it = 0; it < NNUM + 2; ++it) {
                if (wid == 0) {
                    for (int k = 0; k < AW; ++k) {
                        int j = k * 64 + lane;
                        bool nb = false;
                        if (j < NNUM && ((cand[k] >> lane) & 1ULL)) {
                            unsigned long long o =
                                (adj_sh[j][0] & fin[0]) | (adj_sh[j][1] & fin[1]) |
                                (adj_sh[j][2] & fin[2]) | (adj_sh[j][3] & fin[3]) |
                                (adj_sh[j][4] & fin[4]);
                            nb = (o != 0ULL);   // adj symmetric
                        }
                        unsigned long long ball = __ballot(nb);
                        if (lane == 0) nwv[k] = ball;
                    }
                    bool ch = (lane < AW) && (nwv[lane] != fin[lane]);
                    unsigned long long chb = __ballot(ch);
                    if (lane == 0) sh_go = (chb != 0ULL) ? 1 : 0;
                    if (lane < AW) fin[lane] = nwv[lane];
                }
                __syncthreads();
                int go = sh_go;
                __syncthreads();          // all read go before wave0 rewrites it
                if (!go) break;
            }
        }
        if (tid == 0) {
            int cs = 0;
            for (int w = 0; w < AW; ++w) cs += __popcll(fin[w]);
            sh_cf = (float)cs;
        }
        __syncthreads();
        // ---- mini meanmap: only input rows rlo..rhi feed this 16-row tile ----
        int rlo = (tile > 0)  ? tile - 1 : 0;
        int rhi = (tile < 27) ? tile + 1 : 27;
        int nr = rhi - rlo + 1;          // 2 or 3
        if (tid < nr * 28) {
            int r = rlo + tid / 28, x = tid - (tid / 28) * 28;
            float a = 0.f;
            for (int w = 0; w < AW; ++w) {
                unsigned long long word = fin[w];
                while (word) {
                    int j = w * 64 + (__ffsll(word) - 1);
                    word &= word - 1;
                    a += g_rm[((size_t)b * NNUM + j) * HW + r * 28 + x];
                }
            }
            mrow[tid] = __fdiv_rn(a, sh_cf);
        }
        __syncthreads();
        int row0 = tile * RT;
        {   // rowY for all 448 (r, x) pairs
            int r = tid / 28, x = tid - (tid / 28) * 28;
            int oy = row0 + r;
            float iy = fmaf((float)oy, 0.0625f, -0.46875f);   // (oy+0.5)/16-0.5, exact
            float y0f = floorf(iy);
            float wy = iy - y0f;
            int y0 = (int)y0f;
            if (y0 < 0) { y0 = 0; wy = 0.0f; } else if (y0 > 26) { y0 = 26; wy = 1.0f; }
            float lo = mrow[(y0 - rlo) * 28 + x], hi = mrow[(y0 - rlo + 1) * 28 + x];
            rowY[tid] = lo + wy * (hi - lo);
        }
        __syncthreads();
        double acc = 0.0;
        {
            int r = tid / 28, j = tid - (tid / 28) * 28;
            const int* gr = gt + ((size_t)b * GH + row0 + r) * GH;
            int cp1 = c + 1;
            if (j < 27) {
                float rY0 = rowY[r * 28 + j], rY1 = rowY[r * 28 + j + 1];
                float sl = rY1 - rY0;
                const int4* gp = (const int4*)(gr + 16 * j + 8);
                #pragma unroll
                for (int q = 0; q < 4; ++q) {
                    int4 g4 = gp[q];
                    #pragma unroll
                    for (int uu = 0; uu < 4; ++uu) {
                        int k = q * 4 + uu;
                        int gv = (uu == 0) ? g4.x : (uu == 1) ? g4.y : (uu == 2) ? g4.z : g4.w;
                        float wk = fmaf((float)k, 0.0625f, 0.03125f);   // (2k+1)/32, exact
                        float pred = rY0 + wk * sl;
                        float xv = (gv == cp1) ? pred : 1.0f - pred;
                        float lg = __logf(fmaxf(xv, 1.175494351e-38f));
                        acc += (double)((xv > 0.0f) ? lg : -100.0f);
                    }
                }
            } else {
                #pragma unroll
                for (int side = 0; side < 2; ++side) {
                    float pred = rowY[r * 28 + (side ? 27 : 0)];
                    const int4* gp = (const int4*)(gr + (side ? 440 : 0));
                    int4 a0 = gp[0], a1 = gp[1];
                    int np = (a0.x == cp1) + (a0.y == cp1) + (a0.z == cp1) + (a0.w == cp1)
                           + (a1.x == cp1) + (a1.y == cp1) + (a1.z == cp1) + (a1.w == cp1);
                    float om = 1.0f - pred;
                    float lgp = (pred > 0.0f) ? __logf(fmaxf(pred, 1.175494351e-38f)) : -100.0f;
                    float lgn = (om   > 0.0f) ? __logf(fmaxf(om,   1.175494351e-38f)) : -100.0f;
                    acc += (double)lgp * (double)np + (double)lgn * (double)(8 - np);
                }
            }
        }
        #pragma unroll
        for (int off = 32; off; off >>= 1) acc += __shfl_xor(acc, off);
        if (lane == 0) wsum[wid] = acc;
        __syncthreads();
        if (tid == 0) {
            double s = 0.0;
            #pragma unroll
            for (int w = 0; w < 7; ++w) s += wsum[w];
            g_part[blk] = -s * (1.0 / (448.0 * 448.0));
        }
    }

    // ---- spin-free hierarchical completion; overall-last block reduces ----
    if (tid == 0) {
        sh_last = 0;
        __builtin_amdgcn_fence(__ATOMIC_RELEASE, "agent");   // g_part visible before arrival
        int t = __hip_atomic_fetch_add(&g_tdone[bc], 1, __ATOMIC_ACQ_REL, __HIP_MEMORY_SCOPE_AGENT);
        if (t == NTILE - 1) {
            __hip_atomic_store(&g_tdone[bc], 0, __ATOMIC_RELAXED, __HIP_MEMORY_SCOPE_AGENT);
            int d = __hip_atomic_fetch_add(&g_bdone, 1, __ATOMIC_ACQ_REL, __HIP_MEMORY_SCOPE_AGENT);
            if (d == TOTBC - 1) {
                __hip_atomic_store(&g_bdone, 0, __ATOMIC_RELAXED, __HIP_MEMORY_SCOPE_AGENT);
                sh_last = 1;
            }
        }
    }
    __syncthreads();
    if (sh_last) {
        __builtin_amdgcn_fence(__ATOMIC_ACQUIRE, "agent");   // see all g_part across XCDs
        if (tid == 0) sh_sa = 0;
        __syncthreads();
        double s = 0.0;
        for (int i = tid; i < TOTBLK; i += 448) s += g_part[i];
        #pragma unroll
        for (int off = 32; off; off >>= 1) s += __shfl_xor(s, off);
        if (lane == 0) wsum[wid] = s;
        if (tid < TOTBC && label[tid] != 0) atomicAdd(&sh_sa, 1);
        __syncthreads();
        if (tid == 0) {
            double tot = 0.0;
            #pragma unroll
            for (int w = 0; w < 7; ++w) tot += wsum[w];
            out[0] = (float)(tot / (double)sh_sa);
        }
    }
}

extern "C" void kernel_launch(void* const* d_in, const int* in_sizes, int n_in,
                              void* d_out, int out_size, void* d_ws, size_t ws_size,
                              hipStream_t stream) {
    const float* smap  = (const float*)d_in[0];   // (L,B,N,784)
    const float* score = (const float*)d_in[1];   // (B,N,C)
    const int*   label = (const int*)d_in[2];     // (B,C)
    const int*   gt    = (const int*)d_in[3];     // (B,448,448)
    float* out = (float*)d_out;

    hipLaunchKernelGGL(k_rm,  dim3(BNUM * NNUM), dim3(256), 0, stream, smap);
    hipLaunchKernelGGL(k_adj, dim3(BNUM * NNUM), dim3(320), 0, stream);
    hipLaunchKernelGGL(k_bcf, dim3(TOTBLK),      dim3(448), 0, stream, score, label, gt, out);
}

// Round 6
// 116.126 us; speedup vs baseline: 3.9833x; 1.6344x over previous
//
#include <hip/hip_runtime.h>
#include <math.h>

#define LNUM 6
#define BNUM 8
#define NNUM 300
#define CNUM 20
#define HW   784
#define HW4  196   // HW/4
#define GH   448
#define NW   16    // mask words per (b,n): permuted bit order (popcount-invariant)
#define AW   5     // adjacency row words (300 bits -> 5 x u64)
#define RT   16    // bce rows per tile
#define NTILE 28   // 448/16 tiles per (b,c)
#define TOTBC  (BNUM*CNUM)          // 160
#define TOTBLK (TOTBC*NTILE)        // 4480

// ---- device scratch (every consumed entry rewritten each launch; acc/counter self-reset) ----
__device__ float              g_rm [BNUM*NNUM*HW];
__device__ unsigned long long g_T  [BNUM*NNUM*NW];
__device__ int                g_s  [BNUM*NNUM];
__device__ unsigned long long g_adj[BNUM*NNUM*AW];
__device__ float              g_mm [BNUM*CNUM*HW];
__device__ double             g_acc  = 0.0;   // reset by last block each launch
__device__ int                g_done = 0;     // reset by last block each launch

// One block per (b,n): mean over L (float4), relu, max-normalize, rm + bitmask + popcount.
__global__ void k_rm(const float* __restrict__ sm) {
    int bn  = blockIdx.x;
    int tid = threadIdx.x;               // 256
    int lane = tid & 63, wid = tid >> 6;
    __shared__ float wmax[4];
    __shared__ int   scount;
    if (tid == 0) scount = 0;
    const size_t lstr4 = (size_t)BNUM * NNUM * HW4;
    const float4* base = (const float4*)sm + (size_t)bn * HW4;
    bool act = tid < HW4;
    float4 v = {0.f, 0.f, 0.f, 0.f};
    if (act) {
        float4 a = {0.f, 0.f, 0.f, 0.f};
        #pragma unroll
        for (int l = 0; l < LNUM; ++l) {
            float4 x = base[(size_t)l * lstr4 + tid];
            a.x += x.x; a.y += x.y; a.z += x.z; a.w += x.w;
        }
        v.x = fmaxf(__fdiv_rn(a.x, 6.0f), 0.0f);
        v.y = fmaxf(__fdiv_rn(a.y, 6.0f), 0.0f);
        v.z = fmaxf(__fdiv_rn(a.z, 6.0f), 0.0f);
        v.w = fmaxf(__fdiv_rn(a.w, 6.0f), 0.0f);
    }
    float lm = fmaxf(fmaxf(v.x, v.y), fmaxf(v.z, v.w));
    #pragma unroll
    for (int off = 32; off; off >>= 1) lm = fmaxf(lm, __shfl_xor(lm, off));
    if (lane == 0) wmax[wid] = lm;
    __syncthreads();
    float mx = fmaxf(fmaxf(wmax[0], wmax[1]), fmaxf(wmax[2], wmax[3]));
    float d = mx + 1e-6f;
    float4 nv;
    nv.x = __fdiv_rn(v.x, d); nv.y = __fdiv_rn(v.y, d);
    nv.z = __fdiv_rn(v.z, d); nv.w = __fdiv_rn(v.w, d);
    if (act) ((float4*)g_rm)[(size_t)bn * HW4 + tid] = nv;
    float c[4] = {nv.x, nv.y, nv.z, nv.w};
    #pragma unroll
    for (int k = 0; k < 4; ++k) {
        bool pr = act && (c[k] > 0.7f);
        unsigned long long ball = __ballot(pr);
        if (lane == 0) {
            g_T[(size_t)bn * NW + k * 4 + wid] = ball;
            atomicAdd(&scount, __popcll(ball));
        }
    }
    __syncthreads();
    if (tid == 0) g_s[bn] = scount;
}

// One block per (b,i): adjacency row i via popcount(AND) + exact f32 (iou+dice)/2 > 0.5
__global__ void k_adj() {
    int blk = blockIdx.x;                // b*300 + i
    int b = blk / NNUM;
    int tid = threadIdx.x;               // 320 (5 waves)
    __shared__ unsigned long long Ti[NW];
    __shared__ int si_sh;
    if (tid < NW)  Ti[tid] = g_T[(size_t)blk * NW + tid];
    if (tid == NW) si_sh = g_s[blk];
    __syncthreads();
    bool a = false;
    int j = tid;
    if (j < NNUM) {
        const unsigned long long* Tj = &g_T[((size_t)b * NNUM + j) * NW];
        int inter = 0;
        #pragma unroll
        for (int w = 0; w < NW; ++w) inter += __popcll(Ti[w] & Tj[w]);
        int si = si_sh, sj = g_s[b * NNUM + j];
        int uni = si + sj - inter, tot = si + sj;
        float iou  = (uni == 0) ? 1.0f : __fdiv_rn((float)inter, (float)uni);
        float dice = (tot == 0) ? 1.0f : __fdiv_rn(2.0f * (float)inter, (float)tot);
        a = (0.5f * (iou + dice)) > 0.5f;
    }
    unsigned long long ball = __ballot(a);
    if ((tid & 63) == 0) g_adj[(size_t)blk * AW + (tid >> 6)] = ball;
}

// One block per active (b,c), 320 threads: FULLY PARALLEL cluster fixed point
// (j = tid, all 300 new[j] per iteration) + float4 meanmap.
__global__ void __launch_bounds__(320)
k_cm(const float* __restrict__ score, const int* __restrict__ label) {
    int blk = blockIdx.x;                // b*C + c
    if (label[blk] == 0) return;         // block-uniform, before any barrier
    int b = blk / CNUM, c = blk - b * CNUM;
    int tid = threadIdx.x;               // 320 (5 waves)
    int lane = tid & 63, wid = tid >> 6;
    __shared__ unsigned long long adj_sh[NNUM][AW];
    __shared__ unsigned long long cand[AW], fin[AW], nwv[AW];
    __shared__ float wbv[AW], wbva[AW];
    __shared__ int   wbi[AW], wbia[AW];
    __shared__ int sh_has, sh_go;
    __shared__ float sh_cf;
    for (int idx = tid; idx < NNUM * AW; idx += 320)
        ((unsigned long long*)adj_sh)[idx] = g_adj[(size_t)b * NNUM * AW + idx];
    // ---- cand bits + per-wave argmaxes (parallel over 5 waves) ----
    int j = tid;
    bool cb = false;
    float sc = -INFINITY;
    if (j < NNUM) {
        sc = score[((size_t)b * NNUM + j) * CNUM + c];
        cb = sc > 0.01f;
    }
    unsigned long long ball = __ballot(cb);
    if (lane == 0) cand[wid] = ball;
    float bv  = cb ? sc : -INFINITY;          int bi  = cb ? j : NNUM;
    float bva = (j < NNUM) ? sc : -INFINITY;  int bia = (j < NNUM) ? j : NNUM;
    #pragma unroll
    for (int off = 1; off < 64; off <<= 1) {
        float ov = __shfl_xor(bv, off);  int oi = __shfl_xor(bi, off);
        if (ov > bv || (ov == bv && oi < bi)) { bv = ov; bi = oi; }
        float ova = __shfl_xor(bva, off); int oia = __shfl_xor(bia, off);
        if (ova > bva || (ova == bva && oia < bia)) { bva = ova; bia = oia; }
    }
    if (lane == 0) { wbv[wid] = bv; wbi[wid] = bi; wbva[wid] = bva; wbia[wid] = bia; }
    __syncthreads();
    if (tid == 0) {
        // combine waves in ascending index order: strict > keeps first occurrence
        float cv = -INFINITY; int ci = NNUM;
        float cva = -INFINITY; int cia = NNUM;
        #pragma unroll
        for (int w = 0; w < AW; ++w) {
            if (wbv[w] > cv)  { cv = wbv[w];  ci = wbi[w]; }
            if (wbva[w] > cva) { cva = wbva[w]; cia = wbia[w]; }
        }
        bool has = (cand[0] | cand[1] | cand[2] | cand[3] | cand[4]) != 0ULL;
        sh_has = has ? 1 : 0;
        if (has) {
            #pragma unroll
            for (int w = 0; w < AW; ++w) fin[w] = cand[w] & adj_sh[ci][w];
        } else {
            #pragma unroll
            for (int w = 0; w < AW; ++w)
                fin[w] = ((cia >> 6) == w) ? (1ULL << (cia & 63)) : 0ULL;
        }
    }
    __syncthreads();
    if (sh_has) {
        bool cj = cb;                     // candidate bit for my j (j<NNUM only)
        for (int it = 0; it < NNUM + 2; ++it) {
            bool nb = false;
            if (j < NNUM && cj) {
                unsigned long long o =
                    (adj_sh[j][0] & fin[0]) | (adj_sh[j][1] & fin[1]) |
                    (adj_sh[j][2] & fin[2]) | (adj_sh[j][3] & fin[3]) |
                    (adj_sh[j][4] & fin[4]);
                nb = (o != 0ULL);         // adj symmetric: row j == column j
            }
            unsigned long long nball = __ballot(nb);
            if (lane == 0) nwv[wid] = nball;
            __syncthreads();
            if (wid == 0) {
                bool ch = (lane < AW) && (nwv[lane] != fin[lane]);
                unsigned long long chb = __ballot(ch);
                if (lane == 0) sh_go = (chb != 0ULL) ? 1 : 0;
                if (lane < AW) fin[lane] = nwv[lane];
            }
            __syncthreads();
            if (!sh_go) break;            // wave0 rewrites sh_go only after next barrier
        }
    }
    if (tid == 0) {
        int cs = 0;
        for (int w = 0; w < AW; ++w) cs += __popcll(fin[w]);
        sh_cf = (float)cs;
    }
    __syncthreads();
    // ---- meanmap: float4 accumulation over selected rows ----
    if (tid < HW4) {
        float4 a = {0.f, 0.f, 0.f, 0.f};
        for (int w = 0; w < AW; ++w) {
            unsigned long long word = fin[w];
            while (word) {
                int jj = w * 64 + (__ffsll(word) - 1);
                word &= word - 1;
                float4 r = ((const float4*)g_rm)[((size_t)b * NNUM + jj) * HW4 + tid];
                a.x += r.x; a.y += r.y; a.z += r.z; a.w += r.w;
            }
        }
        float cdiv = sh_cf;
        float4 o;
        o.x = __fdiv_rn(a.x, cdiv); o.y = __fdiv_rn(a.y, cdiv);
        o.z = __fdiv_rn(a.z, cdiv); o.w = __fdiv_rn(a.w, cdiv);
        ((float4*)g_mm)[(size_t)blk * HW4 + tid] = o;
    }
}

// Fused bilinear upsample (28->448) + BCE + spin-free fenceless finalization:
// per-block device-scope f64 atomicAdd (executes at coherence point), vmcnt drain,
// relaxed done-counter; 4480th block reads+resets via atomicExch and writes out.
__global__ void __launch_bounds__(448)
k_bce(const int* __restrict__ gt, const int* __restrict__ label, float* __restrict__ out) {
    int blk = blockIdx.x;                // bc*NTILE + tile
    int bc = blk / NTILE, tile = blk - bc * NTILE;
    int tid = threadIdx.x;               // 448 (7 waves)
    int lane = tid & 63, wid = tid >> 6;
    __shared__ float m[HW];
    __shared__ float rowY[RT * 28];
    __shared__ double wsum[7];
    __shared__ int sh_last, sh_sa;
    bool active = (label[bc] != 0);      // block-uniform
    if (active) {
        int b = bc / CNUM, c = bc - b * CNUM;
        if (tid < HW4) ((float4*)m)[tid] = ((const float4*)g_mm)[(size_t)bc * HW4 + tid];
        __syncthreads();
        int row0 = tile * RT;
        {
            int r = tid / 28, x = tid - (tid / 28) * 28;
            int oy = row0 + r;
            float iy = fmaf((float)oy, 0.0625f, -0.46875f);   // (oy+0.5)/16-0.5, exact
            float y0f = floorf(iy);
            float wy = iy - y0f;
            int y0 = (int)y0f;
            if (y0 < 0) { y0 = 0; wy = 0.0f; } else if (y0 > 26) { y0 = 26; wy = 1.0f; }
            float lo = m[y0 * 28 + x], hi = m[y0 * 28 + 28 + x];
            rowY[tid] = lo + wy * (hi - lo);
        }
        __syncthreads();
        double acc = 0.0;
        {
            int r = tid / 28, j = tid - (tid / 28) * 28;
            const int* gr = gt + ((size_t)b * GH + row0 + r) * GH;
            int cp1 = c + 1;
            if (j < 27) {
                float rY0 = rowY[r * 28 + j], rY1 = rowY[r * 28 + j + 1];
                float sl = rY1 - rY0;
                const int4* gp = (const int4*)(gr + 16 * j + 8);
                #pragma unroll
                for (int q = 0; q < 4; ++q) {
                    int4 g4 = gp[q];
                    #pragma unroll
                    for (int uu = 0; uu < 4; ++uu) {
                        int k = q * 4 + uu;
                        int gv = (uu == 0) ? g4.x : (uu == 1) ? g4.y : (uu == 2) ? g4.z : g4.w;
                        float wk = fmaf((float)k, 0.0625f, 0.03125f);   // (2k+1)/32, exact
                        float pred = rY0 + wk * sl;
                        float xv = (gv == cp1) ? pred : 1.0f - pred;
                        float lg = __logf(fmaxf(xv, 1.175494351e-38f));
                        acc += (double)((xv > 0.0f) ? lg : -100.0f);
                    }
                }
            } else {
                #pragma unroll
                for (int side = 0; side < 2; ++side) {
                    float pred = rowY[r * 28 + (side ? 27 : 0)];
                    const int4* gp = (const int4*)(gr + (side ? 440 : 0));
                    int4 a0 = gp[0], a1 = gp[1];
                    int np = (a0.x == cp1) + (a0.y == cp1) + (a0.z == cp1) + (a0.w == cp1)
                           + (a1.x == cp1) + (a1.y == cp1) + (a1.z == cp1) + (a1.w == cp1);
                    float om = 1.0f - pred;
                    float lgp = (pred > 0.0f) ? __logf(fmaxf(pred, 1.175494351e-38f)) : -100.0f;
                    float lgn = (om   > 0.0f) ? __logf(fmaxf(om,   1.175494351e-38f)) : -100.0f;
                    acc += (double)lgp * (double)np + (double)lgn * (double)(8 - np);
                }
            }
        }
        #pragma unroll
        for (int off = 32; off; off >>= 1) acc += __shfl_xor(acc, off);
        if (lane == 0) wsum[wid] = acc;
        __syncthreads();
        if (tid == 0) {
            double s = 0.0;
            #pragma unroll
            for (int w = 0; w < 7; ++w) s += wsum[w];
            atomicAdd(&g_acc, -s * (1.0 / (448.0 * 448.0)));   // device-scope, at MALL
            asm volatile("s_waitcnt vmcnt(0)" ::: "memory");    // add complete before counter
        }
    }
    if (tid == 0) {
        int d = __hip_atomic_fetch_add(&g_done, 1, __ATOMIC_RELAXED, __HIP_MEMORY_SCOPE_AGENT);
        sh_last = (d == TOTBLK - 1) ? 1 : 0;
    }
    __syncthreads();
    if (sh_last) {
        if (tid == 0) {
            // read + reset in one RMW at the coherence point; all adds are ordered
            // before their counter increments, and we observed the last increment.
            unsigned long long bits = atomicExch((unsigned long long*)&g_acc, 0ULL);
            double tot = __longlong_as_double(bits);
            atomicExch(&g_done, 0);
            sh_sa = 0;
            wsum[0] = tot;
        }
        __syncthreads();
        if (tid < TOTBC && label[tid] != 0) atomicAdd(&sh_sa, 1);
        __syncthreads();
        if (tid == 0) out[0] = (float)(wsum[0] / (double)sh_sa);
    }
}

extern "C" void kernel_launch(void* const* d_in, const int* in_sizes, int n_in,
                              void* d_out, int out_size, void* d_ws, size_t ws_size,
                              hipStream_t stream) {
    const float* smap  = (const float*)d_in[0];   // (L,B,N,784)
    const float* score = (const float*)d_in[1];   // (B,N,C)
    const int*   label = (const int*)d_in[2];     // (B,C)
    const int*   gt    = (const int*)d_in[3];     // (B,448,448)
    float* out = (float*)d_out;

    hipLaunchKernelGGL(k_rm,  dim3(BNUM * NNUM), dim3(256), 0, stream, smap);
    hipLaunchKernelGGL(k_adj, dim3(BNUM * NNUM), dim3(320), 0, stream);
    hipLaunchKernelGGL(k_cm,  dim3(TOTBC),       dim3(320), 0, stream, score, label);
    hipLaunchKernelGGL(k_bce, dim3(TOTBLK),      dim3(448), 0, stream, gt, label, out);
}

// Round 7
// 54.228 us; speedup vs baseline: 8.5299x; 2.1414x over previous
//
#include <hip/hip_runtime.h>
#include <math.h>

#define LNUM 6
#define BNUM 8
#define NNUM 300
#define CNUM 20
#define HW   784
#define HW4  196   // HW/4
#define GH   448
#define NW   16    // mask words per (b,n): permuted bit order (popcount-invariant)
#define AW   5     // adjacency row words (300 bits -> 5 x u64)
#define RT   16    // bce rows per tile
#define NTILE 28   // 448/16 tiles per (b,c)
#define TOTBC  (BNUM*CNUM)          // 160
#define TOTBLK (TOTBC*NTILE)        // 4480

// ---- device scratch (every consumed entry rewritten each launch; counters/acc self-reset) ----
__device__ float              g_rm [BNUM*NNUM*HW];
__device__ unsigned long long g_T  [BNUM*NNUM*NW];
__device__ int                g_s  [BNUM*NNUM];
__device__ unsigned long long g_adj[BNUM*NNUM*AW];
__device__ float              g_mm [BNUM*CNUM*HW];
// one 128-B cacheline per bc -> no cross-bc atomic serialization
struct PadD { double v; double pad[15]; };
struct PadI { int v;    int    pad[31]; };
__device__ PadD g_accbc[TOTBC];   // f64 partial per bc; exchanged to 0 by final block
__device__ PadI g_tdone[TOTBC];   // tile-done per bc; reset by bc-last
__device__ int  g_bdone = 0;      // bc-done (single root line); reset by final block

// One block per (b,n): mean over L (float4), relu, max-normalize, rm + bitmask + popcount.
__global__ void k_rm(const float* __restrict__ sm) {
    int bn  = blockIdx.x;
    int tid = threadIdx.x;               // 256
    int lane = tid & 63, wid = tid >> 6;
    __shared__ float wmax[4];
    __shared__ int   scount;
    if (tid == 0) scount = 0;
    const size_t lstr4 = (size_t)BNUM * NNUM * HW4;
    const float4* base = (const float4*)sm + (size_t)bn * HW4;
    bool act = tid < HW4;
    float4 v = {0.f, 0.f, 0.f, 0.f};
    if (act) {
        float4 a = {0.f, 0.f, 0.f, 0.f};
        #pragma unroll
        for (int l = 0; l < LNUM; ++l) {
            float4 x = base[(size_t)l * lstr4 + tid];
            a.x += x.x; a.y += x.y; a.z += x.z; a.w += x.w;
        }
        v.x = fmaxf(__fdiv_rn(a.x, 6.0f), 0.0f);
        v.y = fmaxf(__fdiv_rn(a.y, 6.0f), 0.0f);
        v.z = fmaxf(__fdiv_rn(a.z, 6.0f), 0.0f);
        v.w = fmaxf(__fdiv_rn(a.w, 6.0f), 0.0f);
    }
    float lm = fmaxf(fmaxf(v.x, v.y), fmaxf(v.z, v.w));
    #pragma unroll
    for (int off = 32; off; off >>= 1) lm = fmaxf(lm, __shfl_xor(lm, off));
    if (lane == 0) wmax[wid] = lm;
    __syncthreads();
    float mx = fmaxf(fmaxf(wmax[0], wmax[1]), fmaxf(wmax[2], wmax[3]));
    float d = mx + 1e-6f;
    float4 nv;
    nv.x = __fdiv_rn(v.x, d); nv.y = __fdiv_rn(v.y, d);
    nv.z = __fdiv_rn(v.z, d); nv.w = __fdiv_rn(v.w, d);
    if (act) ((float4*)g_rm)[(size_t)bn * HW4 + tid] = nv;
    float c[4] = {nv.x, nv.y, nv.z, nv.w};
    #pragma unroll
    for (int k = 0; k < 4; ++k) {
        bool pr = act && (c[k] > 0.7f);
        unsigned long long ball = __ballot(pr);
        if (lane == 0) {
            g_T[(size_t)bn * NW + k * 4 + wid] = ball;
            atomicAdd(&scount, __popcll(ball));
        }
    }
    __syncthreads();
    if (tid == 0) g_s[bn] = scount;
}

// One block per (b,i): adjacency row i via popcount(AND) + exact f32 (iou+dice)/2 > 0.5
__global__ void k_adj() {
    int blk = blockIdx.x;                // b*300 + i
    int b = blk / NNUM;
    int tid = threadIdx.x;               // 320 (5 waves)
    __shared__ unsigned long long Ti[NW];
    __shared__ int si_sh;
    if (tid < NW)  Ti[tid] = g_T[(size_t)blk * NW + tid];
    if (tid == NW) si_sh = g_s[blk];
    __syncthreads();
    bool a = false;
    int j = tid;
    if (j < NNUM) {
        const unsigned long long* Tj = &g_T[((size_t)b * NNUM + j) * NW];
        int inter = 0;
        #pragma unroll
        for (int w = 0; w < NW; ++w) inter += __popcll(Ti[w] & Tj[w]);
        int si = si_sh, sj = g_s[b * NNUM + j];
        int uni = si + sj - inter, tot = si + sj;
        float iou  = (uni == 0) ? 1.0f : __fdiv_rn((float)inter, (float)uni);
        float dice = (tot == 0) ? 1.0f : __fdiv_rn(2.0f * (float)inter, (float)tot);
        a = (0.5f * (iou + dice)) > 0.5f;
    }
    unsigned long long ball = __ballot(a);
    if ((tid & 63) == 0) g_adj[(size_t)blk * AW + (tid >> 6)] = ball;
}

// One block per active (b,c), 320 threads: FULLY PARALLEL cluster fixed point
// (j = tid, all 300 new[j] per iteration) + float4 meanmap.
__global__ void __launch_bounds__(320)
k_cm(const float* __restrict__ score, const int* __restrict__ label) {
    int blk = blockIdx.x;                // b*C + c
    if (label[blk] == 0) return;         // block-uniform, before any barrier
    int b = blk / CNUM, c = blk - b * CNUM;
    int tid = threadIdx.x;               // 320 (5 waves)
    int lane = tid & 63, wid = tid >> 6;
    __shared__ unsigned long long adj_sh[NNUM][AW];
    __shared__ unsigned long long cand[AW], fin[AW], nwv[AW];
    __shared__ float wbv[AW], wbva[AW];
    __shared__ int   wbi[AW], wbia[AW];
    __shared__ int sh_has, sh_go;
    __shared__ float sh_cf;
    for (int idx = tid; idx < NNUM * AW; idx += 320)
        ((unsigned long long*)adj_sh)[idx] = g_adj[(size_t)b * NNUM * AW + idx];
    // ---- cand bits + per-wave argmaxes (parallel over 5 waves) ----
    int j = tid;
    bool cb = false;
    float sc = -INFINITY;
    if (j < NNUM) {
        sc = score[((size_t)b * NNUM + j) * CNUM + c];
        cb = sc > 0.01f;
    }
    unsigned long long ball = __ballot(cb);
    if (lane == 0) cand[wid] = ball;
    float bv  = cb ? sc : -INFINITY;          int bi  = cb ? j : NNUM;
    float bva = (j < NNUM) ? sc : -INFINITY;  int bia = (j < NNUM) ? j : NNUM;
    #pragma unroll
    for (int off = 1; off < 64; off <<= 1) {
        float ov = __shfl_xor(bv, off);  int oi = __shfl_xor(bi, off);
        if (ov > bv || (ov == bv && oi < bi)) { bv = ov; bi = oi; }
        float ova = __shfl_xor(bva, off); int oia = __shfl_xor(bia, off);
        if (ova > bva || (ova == bva && oia < bia)) { bva = ova; bia = oia; }
    }
    if (lane == 0) { wbv[wid] = bv; wbi[wid] = bi; wbva[wid] = bva; wbia[wid] = bia; }
    __syncthreads();
    if (tid == 0) {
        // combine waves in ascending index order: strict > keeps first occurrence
        float cv = -INFINITY; int ci = NNUM;
        float cva = -INFINITY; int cia = NNUM;
        #pragma unroll
        for (int w = 0; w < AW; ++w) {
            if (wbv[w] > cv)  { cv = wbv[w];  ci = wbi[w]; }
            if (wbva[w] > cva) { cva = wbva[w]; cia = wbia[w]; }
        }
        bool has = (cand[0] | cand[1] | cand[2] | cand[3] | cand[4]) != 0ULL;
        sh_has = has ? 1 : 0;
        if (has) {
            #pragma unroll
            for (int w = 0; w < AW; ++w) fin[w] = cand[w] & adj_sh[ci][w];
        } else {
            #pragma unroll
            for (int w = 0; w < AW; ++w)
                fin[w] = ((cia >> 6) == w) ? (1ULL << (cia & 63)) : 0ULL;
        }
    }
    __syncthreads();
    if (sh_has) {
        bool cj = cb;                     // candidate bit for my j (j<NNUM only)
        for (int it = 0; it < NNUM + 2; ++it) {
            bool nb = false;
            if (j < NNUM && cj) {
                unsigned long long o =
                    (adj_sh[j][0] & fin[0]) | (adj_sh[j][1] & fin[1]) |
                    (adj_sh[j][2] & fin[2]) | (adj_sh[j][3] & fin[3]) |
                    (adj_sh[j][4] & fin[4]);
                nb = (o != 0ULL);         // adj symmetric: row j == column j
            }
            unsigned long long nball = __ballot(nb);
            if (lane == 0) nwv[wid] = nball;
            __syncthreads();
            if (wid == 0) {
                bool ch = (lane < AW) && (nwv[lane] != fin[lane]);
                unsigned long long chb = __ballot(ch);
                if (lane == 0) sh_go = (chb != 0ULL) ? 1 : 0;
                if (lane < AW) fin[lane] = nwv[lane];
            }
            __syncthreads();
            if (!sh_go) break;            // wave0 rewrites sh_go only after next barrier
        }
    }
    if (tid == 0) {
        int cs = 0;
        for (int w = 0; w < AW; ++w) cs += __popcll(fin[w]);
        sh_cf = (float)cs;
    }
    __syncthreads();
    // ---- meanmap: float4 accumulation over selected rows ----
    if (tid < HW4) {
        float4 a = {0.f, 0.f, 0.f, 0.f};
        for (int w = 0; w < AW; ++w) {
            unsigned long long word = fin[w];
            while (word) {
                int jj = w * 64 + (__ffsll(word) - 1);
                word &= word - 1;
                float4 r = ((const float4*)g_rm)[((size_t)b * NNUM + jj) * HW4 + tid];
                a.x += r.x; a.y += r.y; a.z += r.z; a.w += r.w;
            }
        }
        float cdiv = sh_cf;
        float4 o;
        o.x = __fdiv_rn(a.x, cdiv); o.y = __fdiv_rn(a.y, cdiv);
        o.z = __fdiv_rn(a.z, cdiv); o.w = __fdiv_rn(a.w, cdiv);
        ((float4*)g_mm)[(size_t)blk * HW4 + tid] = o;
    }
}

// Fused bilinear upsample (28->448) + BCE + spread hierarchical fenceless finalization.
// Data path is atomic-only (MALL), so no cross-XCD cache staleness; each counter and
// accumulator sits on its own 128-B line; the single root line sees only 160 RMWs.
__global__ void __launch_bounds__(448)
k_bce(const int* __restrict__ gt, const int* __restrict__ label, float* __restrict__ out) {
    int blk = blockIdx.x;                // bc*NTILE + tile
    int bc = blk / NTILE, tile = blk - bc * NTILE;
    int tid = threadIdx.x;               // 448 (7 waves)
    int lane = tid & 63, wid = tid >> 6;
    __shared__ float m[HW];
    __shared__ float rowY[RT * 28];
    __shared__ double wsum[7];
    __shared__ int sh_last, sh_sa;
    bool active = (label[bc] != 0);      // block-uniform
    if (active) {
        int b = bc / CNUM, c = bc - b * CNUM;
        if (tid < HW4) ((float4*)m)[tid] = ((const float4*)g_mm)[(size_t)bc * HW4 + tid];
        __syncthreads();
        int row0 = tile * RT;
        {
            int r = tid / 28, x = tid - (tid / 28) * 28;
            int oy = row0 + r;
            float iy = fmaf((float)oy, 0.0625f, -0.46875f);   // (oy+0.5)/16-0.5, exact
            float y0f = floorf(iy);
            float wy = iy - y0f;
            int y0 = (int)y0f;
            if (y0 < 0) { y0 = 0; wy = 0.0f; } else if (y0 > 26) { y0 = 26; wy = 1.0f; }
            float lo = m[y0 * 28 + x], hi = m[y0 * 28 + 28 + x];
            rowY[tid] = lo + wy * (hi - lo);
        }
        __syncthreads();
        double acc = 0.0;
        {
            int r = tid / 28, j = tid - (tid / 28) * 28;
            const int* gr = gt + ((size_t)b * GH + row0 + r) * GH;
            int cp1 = c + 1;
            if (j < 27) {
                float rY0 = rowY[r * 28 + j], rY1 = rowY[r * 28 + j + 1];
                float sl = rY1 - rY0;
                const int4* gp = (const int4*)(gr + 16 * j + 8);
                #pragma unroll
                for (int q = 0; q < 4; ++q) {
                    int4 g4 = gp[q];
                    #pragma unroll
                    for (int uu = 0; uu < 4; ++uu) {
                        int k = q * 4 + uu;
                        int gv = (uu == 0) ? g4.x : (uu == 1) ? g4.y : (uu == 2) ? g4.z : g4.w;
                        float wk = fmaf((float)k, 0.0625f, 0.03125f);   // (2k+1)/32, exact
                        float pred = rY0 + wk * sl;
                        float xv = (gv == cp1) ? pred : 1.0f - pred;
                        float lg = __logf(fmaxf(xv, 1.175494351e-38f));
                        acc += (double)((xv > 0.0f) ? lg : -100.0f);
                    }
                }
            } else {
                #pragma unroll
                for (int side = 0; side < 2; ++side) {
                    float pred = rowY[r * 28 + (side ? 27 : 0)];
                    const int4* gp = (const int4*)(gr + (side ? 440 : 0));
                    int4 a0 = gp[0], a1 = gp[1];
                    int np = (a0.x == cp1) + (a0.y == cp1) + (a0.z == cp1) + (a0.w == cp1)
                           + (a1.x == cp1) + (a1.y == cp1) + (a1.z == cp1) + (a1.w == cp1);
                    float om = 1.0f - pred;
                    float lgp = (pred > 0.0f) ? __logf(fmaxf(pred, 1.175494351e-38f)) : -100.0f;
                    float lgn = (om   > 0.0f) ? __logf(fmaxf(om,   1.175494351e-38f)) : -100.0f;
                    acc += (double)lgp * (double)np + (double)lgn * (double)(8 - np);
                }
            }
        }
        #pragma unroll
        for (int off = 32; off; off >>= 1) acc += __shfl_xor(acc, off);
        if (lane == 0) wsum[wid] = acc;
        __syncthreads();
    }
    if (tid == 0) {
        sh_last = 0;
        if (active) {
            double s = 0.0;
            #pragma unroll
            for (int w = 0; w < 7; ++w) s += wsum[w];
            atomicAdd(&g_accbc[bc].v, -s * (1.0 / (448.0 * 448.0)));   // own line per bc
            asm volatile("s_waitcnt vmcnt(0)" ::: "memory");            // add performed
        }
        int t = __hip_atomic_fetch_add(&g_tdone[bc].v, 1, __ATOMIC_RELAXED, __HIP_MEMORY_SCOPE_AGENT);
        if (t == NTILE - 1) {            // all 28 tiles of this bc arrived (adds performed)
            atomicExch(&g_tdone[bc].v, 0);                              // self-reset
            asm volatile("s_waitcnt vmcnt(0)" ::: "memory");
            int d = __hip_atomic_fetch_add(&g_bdone, 1, __ATOMIC_RELAXED, __HIP_MEMORY_SCOPE_AGENT);
            if (d == TOTBC - 1) {        // all 160 bc complete -> all g_accbc final
                atomicExch(&g_bdone, 0); // self-reset
                sh_last = 1;
            }
        }
    }
    __syncthreads();
    if (sh_last) {
        if (tid == 0) sh_sa = 0;
        __syncthreads();
        double s = 0.0;
        if (tid < TOTBC) {
            // read+reset via RMW at the MALL: sees every prior add, leaves 0 for next launch
            unsigned long long bits = atomicExch((unsigned long long*)&g_accbc[tid].v, 0ULL);
            s = __longlong_as_double(bits);
            if (label[tid] != 0) atomicAdd(&sh_sa, 1);
        }
        #pragma unroll
        for (int off = 32; off; off >>= 1) s += __shfl_xor(s, off);
        if (lane == 0) wsum[wid] = s;
        __syncthreads();
        if (tid == 0) {
            double tot = 0.0;
            #pragma unroll
            for (int w = 0; w < 7; ++w) tot += wsum[w];
            out[0] = (float)(tot / (double)sh_sa);
        }
    }
}

extern "C" void kernel_launch(void* const* d_in, const int* in_sizes, int n_in,
                              void* d_out, int out_size, void* d_ws, size_t ws_size,
                              hipStream_t stream) {
    const float* smap  = (const float*)d_in[0];   // (L,B,N,784)
    const float* score = (const float*)d_in[1];   // (B,N,C)
    const int*   label = (const int*)d_in[2];     // (B,C)
    const int*   gt    = (const int*)d_in[3];     // (B,448,448)
    float* out = (float*)d_out;

    hipLaunchKernelGGL(k_rm,  dim3(BNUM * NNUM), dim3(256), 0, stream, smap);
    hipLaunchKernelGGL(k_adj, dim3(BNUM * NNUM), dim3(320), 0, stream);
    hipLaunchKernelGGL(k_cm,  dim3(TOTBC),       dim3(320), 0, stream, score, label);
    hipLaunchKernelGGL(k_bce, dim3(TOTBLK),      dim3(448), 0, stream, gt, label, out);
}